// Round 3
// baseline (3200.669 us; speedup 1.0000x reference)
//
#include <hip/hip_runtime.h>
#include <math.h>

#define B_ 128
#define T_ 100
#define RL 68   // padded row: [0]=f=-1 (zero), [1..64]=data, [65..67]=zero

// ---------------------------------------------------------------------------
// Fast transcendentals (~1e-6 rel err; threshold 1.27e-4)
// ---------------------------------------------------------------------------
__device__ __forceinline__ float frcp_(float x){ return __builtin_amdgcn_rcpf(x); }
__device__ __forceinline__ float fsig_(float x){ return frcp_(1.f + __expf(-x)); }
__device__ __forceinline__ float ftanh_(float x){ float e = __expf(2.f*x); return 1.f - 2.f*frcp_(e+1.f); }

__device__ __forceinline__ float gate1(float zi, float zf, float zo, float zg, float& c){
    float cc = fsig_(zf)*c + fsig_(zi)*ftanh_(zg);
    c = cc;
    return fsig_(zo)*ftanh_(cc);
}

__device__ __forceinline__ void fma4v(float w, float u0,float u1,float u2,float u3, float4& a){
    a.x = fmaf(w,u0,a.x); a.y = fmaf(w,u1,a.y);
    a.z = fmaf(w,u2,a.z); a.w = fmaf(w,u3,a.w);
}

// One input row, 8 output columns, all 4 gates. row -> v[f0-1 .. f0+8].
// wk = wl + (k_row*3)*ROWS + ch*4 ; tap d weights at wk + d*ROWS.
template<int ROWS>
__device__ __forceinline__ void rowacc8(const float* __restrict__ row,
                                        const float* __restrict__ wk,
                                        float4& i0, float4& i1, float4& f0v, float4& f1v,
                                        float4& o0, float4& o1, float4& g0, float4& g1)
{
    float4 pa = *reinterpret_cast<const float4*>(row);
    float4 pb = *reinterpret_cast<const float4*>(row + 4);
    float2 pc = *reinterpret_cast<const float2*>(row + 8);
    float v0=pa.x,v1=pa.y,v2=pa.z,v3=pa.w,v4=pb.x,v5=pb.y,v6=pb.z,v7=pb.w,v8=pc.x,v9=pc.y;
    float4 wa = *reinterpret_cast<const float4*>(wk);
    float4 wb = *reinterpret_cast<const float4*>(wk + ROWS);
    float4 wc = *reinterpret_cast<const float4*>(wk + 2*ROWS);
    fma4v(wa.x, v0,v1,v2,v3, i0);  fma4v(wa.x, v4,v5,v6,v7, i1);
    fma4v(wa.y, v0,v1,v2,v3, f0v); fma4v(wa.y, v4,v5,v6,v7, f1v);
    fma4v(wa.z, v0,v1,v2,v3, o0);  fma4v(wa.z, v4,v5,v6,v7, o1);
    fma4v(wa.w, v0,v1,v2,v3, g0);  fma4v(wa.w, v4,v5,v6,v7, g1);
    fma4v(wb.x, v1,v2,v3,v4, i0);  fma4v(wb.x, v5,v6,v7,v8, i1);
    fma4v(wb.y, v1,v2,v3,v4, f0v); fma4v(wb.y, v5,v6,v7,v8, f1v);
    fma4v(wb.z, v1,v2,v3,v4, o0);  fma4v(wb.z, v5,v6,v7,v8, o1);
    fma4v(wb.w, v1,v2,v3,v4, g0);  fma4v(wb.w, v5,v6,v7,v8, g1);
    fma4v(wc.x, v2,v3,v4,v5, i0);  fma4v(wc.x, v6,v7,v8,v9, i1);
    fma4v(wc.y, v2,v3,v4,v5, f0v); fma4v(wc.y, v6,v7,v8,v9, f1v);
    fma4v(wc.z, v2,v3,v4,v5, o0);  fma4v(wc.z, v6,v7,v8,v9, o1);
    fma4v(wc.w, v2,v3,v4,v5, g0);  fma4v(wc.w, v6,v7,v8,v9, g1);
}

// One input row, 4 output columns, all 4 gates.
template<int ROWS>
__device__ __forceinline__ void rowacc4(const float* __restrict__ row,
                                        const float* __restrict__ wk,
                                        float4& ai, float4& af, float4& ao, float4& ag)
{
    float4 pa = *reinterpret_cast<const float4*>(row);
    float2 pb = *reinterpret_cast<const float2*>(row + 4);
    float v0=pa.x,v1=pa.y,v2=pa.z,v3=pa.w,v4=pb.x,v5=pb.y;
    float4 wa = *reinterpret_cast<const float4*>(wk);
    float4 wb = *reinterpret_cast<const float4*>(wk + ROWS);
    float4 wc = *reinterpret_cast<const float4*>(wk + 2*ROWS);
    fma4v(wa.x, v0,v1,v2,v3, ai); fma4v(wa.y, v0,v1,v2,v3, af);
    fma4v(wa.z, v0,v1,v2,v3, ao); fma4v(wa.w, v0,v1,v2,v3, ag);
    fma4v(wb.x, v1,v2,v3,v4, ai); fma4v(wb.y, v1,v2,v3,v4, af);
    fma4v(wb.z, v1,v2,v3,v4, ao); fma4v(wb.w, v1,v2,v3,v4, ag);
    fma4v(wc.x, v2,v3,v4,v5, ai); fma4v(wc.y, v2,v3,v4,v5, af);
    fma4v(wc.z, v2,v3,v4,v5, ao); fma4v(wc.w, v2,v3,v4,v5, ag);
}

// ---------------------------------------------------------------------------
// Kernel 1: fused encoder. L0: (1+16)->16 (FT=4), L1: (16+32)->32 (FT=8)
// ---------------------------------------------------------------------------
__global__ __launch_bounds__(256, 1) void enc_kernel(
    const float* __restrict__ x,
    const float* __restrict__ w0, const float* __restrict__ b0,
    const float* __restrict__ w1, const float* __restrict__ b1,
    float* __restrict__ seq,
    float* __restrict__ h1f, float* __restrict__ c1f,
    float* __restrict__ h2f, float* __restrict__ c2f)
{
    __shared__ float wl0[51 * 64];
    __shared__ float wl1[144 * 128];
    __shared__ float bs0[64];
    __shared__ float bs1[128];
    __shared__ float xp[RL];
    __shared__ float h0p[16 * RL];
    __shared__ float h1p[32 * RL];

    const int tid = threadIdx.x;
    const int b = blockIdx.x;

    for (int idx = tid; idx < 51 * 64; idx += 256) {
        int k = idx >> 6, r = idx & 63;
        int ch = r >> 2, g = r & 3;
        int ci = k / 3, d = k - ci * 3;
        wl0[idx] = w0[((g * 16 + ch) * 17 + ci) * 9 + d * 3 + 1];
    }
    for (int idx = tid; idx < 144 * 128; idx += 256) {
        int k = idx >> 7, r = idx & 127;
        int ch = r >> 2, g = r & 3;
        int ci = k / 3, d = k - ci * 3;
        wl1[idx] = w1[((g * 32 + ch) * 48 + ci) * 9 + d * 3 + 1];
    }
    if (tid < 64) bs0[tid] = b0[tid];
    if (tid < 128) bs1[tid] = b1[tid];
    for (int i = tid; i < RL; i += 256) xp[i] = 0.f;
    for (int i = tid; i < 16 * RL; i += 256) h0p[i] = 0.f;
    for (int i = tid; i < 32 * RL; i += 256) h1p[i] = 0.f;
    __syncthreads();

    const int chA = tid >> 4, f0A = (tid & 15) * 4;   // L0: 16ch x 16fg, FT=4
    const int chB = tid >> 3, f0B = (tid & 7) * 8;    // L1: 32ch x 8fg, FT=8

    // biases into registers
    const float biA = bs0[chA], bfA = bs0[16 + chA], boA = bs0[32 + chA], bgA = bs0[48 + chA];
    const float biB = bs1[chB], bfB = bs1[32 + chB], boB = bs1[64 + chB], bgB = bs1[96 + chB];

    const float4 z4 = make_float4(0.f, 0.f, 0.f, 0.f);
    float4 cA = z4, cB0 = z4, cB1 = z4;     // cell states live in registers
    float4 hh = z4, hn0 = z4, hn1 = z4;

    float xv = (tid < 64) ? x[(b * T_ + 0) * 64 + tid] : 0.f;

#pragma unroll 1
    for (int t = 0; t < T_; ++t) {
        if (tid < 64) xp[1 + tid] = xv;
        __syncthreads();                                   // A
        if (tid < 64 && t + 1 < T_) xv = x[(b * T_ + t + 1) * 64 + tid];

        // ---- layer 0 ----
        float4 ai = z4, af = z4, ao = z4, ag = z4;
        rowacc4<64>(xp + f0A, wl0 + chA * 4, ai, af, ao, ag);
        const float* wpa = wl0 + 3 * 64 + chA * 4;
#pragma unroll 1
        for (int r = 0; r < 16; ++r)
            rowacc4<64>(h0p + r * RL + f0A, wpa + (r * 3) * 64, ai, af, ao, ag);

        hh.x = gate1(ai.x + biA, af.x + bfA, ao.x + boA, ag.x + bgA, cA.x);
        hh.y = gate1(ai.y + biA, af.y + bfA, ao.y + boA, ag.y + bgA, cA.y);
        hh.z = gate1(ai.z + biA, af.z + bfA, ao.z + boA, ag.z + bgA, cA.z);
        hh.w = gate1(ai.w + biA, af.w + bfA, ao.w + boA, ag.w + bgA, cA.w);
        __syncthreads();                                   // B
        h0p[chA * RL + 1 + f0A]     = hh.x;
        h0p[chA * RL + 1 + f0A + 1] = hh.y;
        h0p[chA * RL + 1 + f0A + 2] = hh.z;
        h0p[chA * RL + 1 + f0A + 3] = hh.w;
        __syncthreads();                                   // C

        // ---- layer 1 ----
        float4 i0 = z4, i1 = z4, f0v = z4, f1v = z4, o0 = z4, o1 = z4, g0 = z4, g1 = z4;
        const float* wpb = wl1 + chB * 4;
#pragma unroll 1
        for (int r = 0; r < 16; ++r)
            rowacc8<128>(h0p + r * RL + f0B, wpb + (r * 3) * 128,
                         i0, i1, f0v, f1v, o0, o1, g0, g1);
#pragma unroll 1
        for (int r = 0; r < 32; ++r)
            rowacc8<128>(h1p + r * RL + f0B, wpb + ((16 + r) * 3) * 128,
                         i0, i1, f0v, f1v, o0, o1, g0, g1);

        hn0.x = gate1(i0.x + biB, f0v.x + bfB, o0.x + boB, g0.x + bgB, cB0.x);
        hn0.y = gate1(i0.y + biB, f0v.y + bfB, o0.y + boB, g0.y + bgB, cB0.y);
        hn0.z = gate1(i0.z + biB, f0v.z + bfB, o0.z + boB, g0.z + bgB, cB0.z);
        hn0.w = gate1(i0.w + biB, f0v.w + bfB, o0.w + boB, g0.w + bgB, cB0.w);
        hn1.x = gate1(i1.x + biB, f1v.x + bfB, o1.x + boB, g1.x + bgB, cB1.x);
        hn1.y = gate1(i1.y + biB, f1v.y + bfB, o1.y + boB, g1.y + bgB, cB1.y);
        hn1.z = gate1(i1.z + biB, f1v.z + bfB, o1.z + boB, g1.z + bgB, cB1.z);
        hn1.w = gate1(i1.w + biB, f1v.w + bfB, o1.w + boB, g1.w + bgB, cB1.w);
        __syncthreads();                                   // D
        h1p[chB * RL + 1 + f0B]     = hn0.x;
        h1p[chB * RL + 1 + f0B + 1] = hn0.y;
        h1p[chB * RL + 1 + f0B + 2] = hn0.z;
        h1p[chB * RL + 1 + f0B + 3] = hn0.w;
        h1p[chB * RL + 1 + f0B + 4] = hn1.x;
        h1p[chB * RL + 1 + f0B + 5] = hn1.y;
        h1p[chB * RL + 1 + f0B + 6] = hn1.z;
        h1p[chB * RL + 1 + f0B + 7] = hn1.w;
        float* sp = &seq[(((size_t)t * B_ + b) * 32 + chB) * 64 + f0B];
        *reinterpret_cast<float4*>(sp)     = hn0;
        *reinterpret_cast<float4*>(sp + 4) = hn1;
    }

    // final states straight from registers (each thread owns its tile)
    *reinterpret_cast<float4*>(&h1f[(b * 16 + chA) * 64 + f0A]) = hh;
    *reinterpret_cast<float4*>(&c1f[(b * 16 + chA) * 64 + f0A]) = cA;
    float* hp2 = &h2f[(b * 32 + chB) * 64 + f0B];
    float* cp2 = &c2f[(b * 32 + chB) * 64 + f0B];
    *reinterpret_cast<float4*>(hp2)     = hn0;
    *reinterpret_cast<float4*>(hp2 + 4) = hn1;
    *reinterpret_cast<float4*>(cp2)     = cB0;
    *reinterpret_cast<float4*>(cp2 + 4) = cB1;
}

// ---------------------------------------------------------------------------
// Kernel 2: decoder L0 (32+32)->32, FT=8; seq updated in place
// ---------------------------------------------------------------------------
__global__ __launch_bounds__(256, 1) void dec0_kernel(
    const float* __restrict__ w, const float* __restrict__ bias,
    float* __restrict__ seq,
    const float* __restrict__ h2f, const float* __restrict__ c2f)
{
    __shared__ float wl[192 * 128];
    __shared__ float bs[128];
    __shared__ float xin[32 * RL];
    __shared__ float hp[32 * RL];

    const int tid = threadIdx.x;
    const int b = blockIdx.x;

    for (int idx = tid; idx < 192 * 128; idx += 256) {
        int k = idx >> 7, r = idx & 127;
        int ch = r >> 2, g = r & 3;
        int ci = k / 3, d = k - ci * 3;
        wl[idx] = w[((g * 32 + ch) * 64 + ci) * 9 + d * 3 + 1];
    }
    if (tid < 128) bs[tid] = bias[tid];
    for (int i = tid; i < 32 * RL; i += 256) { xin[i] = 0.f; hp[i] = 0.f; }
    __syncthreads();

    const int ch = tid >> 3, f0 = (tid & 7) * 8;   // 32ch x 8fg
    const int stid = tid * 8;                      // == ch*64 + f0

    // init h (LDS) and c (registers)
    {
        const float* hs = &h2f[b * 2048 + stid];
        float4 hv0 = *reinterpret_cast<const float4*>(hs);
        float4 hv1 = *reinterpret_cast<const float4*>(hs + 4);
        float* d = &hp[ch * RL + 1 + f0];
        d[0]=hv0.x; d[1]=hv0.y; d[2]=hv0.z; d[3]=hv0.w;
        d[4]=hv1.x; d[5]=hv1.y; d[6]=hv1.z; d[7]=hv1.w;
    }
    float4 c0 = *reinterpret_cast<const float4*>(&c2f[b * 2048 + stid]);
    float4 c1 = *reinterpret_cast<const float4*>(&c2f[b * 2048 + stid + 4]);

    const float bi = bs[ch], bf = bs[32 + ch], bo = bs[64 + ch], bg = bs[96 + ch];
    const float4 z4 = make_float4(0.f, 0.f, 0.f, 0.f);

    float4 nx0 = *reinterpret_cast<const float4*>(&seq[(size_t)b * 2048 + stid]);
    float4 nx1 = *reinterpret_cast<const float4*>(&seq[(size_t)b * 2048 + stid + 4]);

#pragma unroll 1
    for (int t = 0; t < T_; ++t) {
        {   // stage x tile (own row/cols)
            float* d = &xin[ch * RL + 1 + f0];
            d[0]=nx0.x; d[1]=nx0.y; d[2]=nx0.z; d[3]=nx0.w;
            d[4]=nx1.x; d[5]=nx1.y; d[6]=nx1.z; d[7]=nx1.w;
        }
        __syncthreads();                                   // A
        if (t + 1 < T_) {
            const float* s = &seq[((size_t)(t + 1) * B_ + b) * 2048 + stid];
            nx0 = *reinterpret_cast<const float4*>(s);
            nx1 = *reinterpret_cast<const float4*>(s + 4);
        }

        float4 i0 = z4, i1 = z4, f0v = z4, f1v = z4, o0 = z4, o1 = z4, g0 = z4, g1 = z4;
        const float* wp = wl + ch * 4;
#pragma unroll 1
        for (int r = 0; r < 32; ++r)
            rowacc8<128>(xin + r * RL + f0, wp + (r * 3) * 128,
                         i0, i1, f0v, f1v, o0, o1, g0, g1);
#pragma unroll 1
        for (int r = 0; r < 32; ++r)
            rowacc8<128>(hp + r * RL + f0, wp + ((32 + r) * 3) * 128,
                         i0, i1, f0v, f1v, o0, o1, g0, g1);

        float4 hn0, hn1;
        hn0.x = gate1(i0.x + bi, f0v.x + bf, o0.x + bo, g0.x + bg, c0.x);
        hn0.y = gate1(i0.y + bi, f0v.y + bf, o0.y + bo, g0.y + bg, c0.y);
        hn0.z = gate1(i0.z + bi, f0v.z + bf, o0.z + bo, g0.z + bg, c0.z);
        hn0.w = gate1(i0.w + bi, f0v.w + bf, o0.w + bo, g0.w + bg, c0.w);
        hn1.x = gate1(i1.x + bi, f1v.x + bf, o1.x + bo, g1.x + bg, c1.x);
        hn1.y = gate1(i1.y + bi, f1v.y + bf, o1.y + bo, g1.y + bg, c1.y);
        hn1.z = gate1(i1.z + bi, f1v.z + bf, o1.z + bo, g1.z + bg, c1.z);
        hn1.w = gate1(i1.w + bi, f1v.w + bf, o1.w + bo, g1.w + bg, c1.w);
        __syncthreads();                                   // B
        {
            float* d = &hp[ch * RL + 1 + f0];
            d[0]=hn0.x; d[1]=hn0.y; d[2]=hn0.z; d[3]=hn0.w;
            d[4]=hn1.x; d[5]=hn1.y; d[6]=hn1.z; d[7]=hn1.w;
        }
        float* sp = &seq[((size_t)t * B_ + b) * 2048 + stid];
        *reinterpret_cast<float4*>(sp)     = hn0;          // in place
        *reinterpret_cast<float4*>(sp + 4) = hn1;
    }
}

// ---------------------------------------------------------------------------
// Kernel 3: decoder L1 (32+16)->16 (FT=4) + final 1x1 conv
// ---------------------------------------------------------------------------
__global__ __launch_bounds__(256, 1) void dec1_kernel(
    const float* __restrict__ w, const float* __restrict__ bias,
    const float* __restrict__ seq,
    const float* __restrict__ h1f, const float* __restrict__ c1f,
    const float* __restrict__ fw, const float* __restrict__ fb,
    float* __restrict__ out)
{
    __shared__ float wl[144 * 64];
    __shared__ float bs[64];
    __shared__ float xin[32 * RL];
    __shared__ float hp[16 * RL];
    __shared__ float fcw[16];
    __shared__ float fcb;

    const int tid = threadIdx.x;
    const int b = blockIdx.x;

    for (int idx = tid; idx < 144 * 64; idx += 256) {
        int k = idx >> 6, r = idx & 63;
        int ch = r >> 2, g = r & 3;
        int ci = k / 3, d = k - ci * 3;
        wl[idx] = w[((g * 16 + ch) * 48 + ci) * 9 + d * 3 + 1];
    }
    if (tid < 64) bs[tid] = bias[tid];
    if (tid < 16) fcw[tid] = fw[tid];
    if (tid == 16) fcb = fb[0];
    for (int i = tid; i < 32 * RL; i += 256) xin[i] = 0.f;
    for (int i = tid; i < 16 * RL; i += 256) hp[i] = 0.f;
    __syncthreads();

    const int ch = tid >> 4, f0 = (tid & 15) * 4;   // 16ch x 16fg, FT=4
    const int sci = tid >> 3, sfi = (tid & 7) * 8;  // staging coords
    const int stid = tid * 8;

    // init h (LDS) and c (registers)
    if (tid < 128) {
        const float* hs = &h1f[b * 1024 + stid];
        float4 hv0 = *reinterpret_cast<const float4*>(hs);
        float4 hv1 = *reinterpret_cast<const float4*>(hs + 4);
        float* d = &hp[(stid >> 6) * RL + 1 + (stid & 63)];
        d[0]=hv0.x; d[1]=hv0.y; d[2]=hv0.z; d[3]=hv0.w;
        d[4]=hv1.x; d[5]=hv1.y; d[6]=hv1.z; d[7]=hv1.w;
    }
    float4 cc = *reinterpret_cast<const float4*>(&c1f[b * 1024 + ch * 64 + f0]);

    const float bi = bs[ch], bf = bs[16 + ch], bo = bs[32 + ch], bg = bs[48 + ch];
    const float4 z4 = make_float4(0.f, 0.f, 0.f, 0.f);

    float4 nx0 = *reinterpret_cast<const float4*>(&seq[(size_t)b * 2048 + stid]);
    float4 nx1 = *reinterpret_cast<const float4*>(&seq[(size_t)b * 2048 + stid + 4]);
    __syncthreads();

#pragma unroll 1
    for (int t = 0; t < T_; ++t) {
        {
            float* d = &xin[sci * RL + 1 + sfi];
            d[0]=nx0.x; d[1]=nx0.y; d[2]=nx0.z; d[3]=nx0.w;
            d[4]=nx1.x; d[5]=nx1.y; d[6]=nx1.z; d[7]=nx1.w;
        }
        __syncthreads();                                   // A
        if (t + 1 < T_) {
            const float* s = &seq[((size_t)(t + 1) * B_ + b) * 2048 + stid];
            nx0 = *reinterpret_cast<const float4*>(s);
            nx1 = *reinterpret_cast<const float4*>(s + 4);
        }

        float4 ai = z4, af = z4, ao = z4, ag = z4;
        const float* wp = wl + ch * 4;
#pragma unroll 1
        for (int r = 0; r < 32; ++r)
            rowacc4<64>(xin + r * RL + f0, wp + (r * 3) * 64, ai, af, ao, ag);
#pragma unroll 1
        for (int r = 0; r < 16; ++r)
            rowacc4<64>(hp + r * RL + f0, wp + ((32 + r) * 3) * 64, ai, af, ao, ag);

        float4 hh;
        hh.x = gate1(ai.x + bi, af.x + bf, ao.x + bo, ag.x + bg, cc.x);
        hh.y = gate1(ai.y + bi, af.y + bf, ao.y + bo, ag.y + bg, cc.y);
        hh.z = gate1(ai.z + bi, af.z + bf, ao.z + bo, ag.z + bg, cc.z);
        hh.w = gate1(ai.w + bi, af.w + bf, ao.w + bo, ag.w + bg, cc.w);
        __syncthreads();                                   // B
        hp[ch * RL + 1 + f0]     = hh.x;
        hp[ch * RL + 1 + f0 + 1] = hh.y;
        hp[ch * RL + 1 + f0 + 2] = hh.z;
        hp[ch * RL + 1 + f0 + 3] = hh.w;
        __syncthreads();                                   // C

        if (tid < 64) {
            float a = fcb;
#pragma unroll
            for (int k2 = 0; k2 < 16; ++k2)
                a = fmaf(fcw[k2], hp[k2 * RL + 1 + tid], a);
            out[(b * T_ + t) * 64 + tid] = a;
        }
    }
}

// ---------------------------------------------------------------------------
extern "C" void kernel_launch(void* const* d_in, const int* in_sizes, int n_in,
                              void* d_out, int out_size, void* d_ws, size_t ws_size,
                              hipStream_t stream)
{
    (void)in_sizes; (void)n_in; (void)out_size; (void)ws_size;
    const float* x   = (const float*)d_in[0];
    const float* ew0 = (const float*)d_in[1];
    const float* eb0 = (const float*)d_in[2];
    const float* ew1 = (const float*)d_in[3];
    const float* eb1 = (const float*)d_in[4];
    const float* dw0 = (const float*)d_in[5];
    const float* db0 = (const float*)d_in[6];
    const float* dw1 = (const float*)d_in[7];
    const float* db1 = (const float*)d_in[8];
    const float* fw  = (const float*)d_in[9];
    const float* fb  = (const float*)d_in[10];
    float* out = (float*)d_out;

    float* ws  = (float*)d_ws;
    float* seq = ws;                                     // [T][B][32][64]
    float* h1f = seq + (size_t)T_ * B_ * 32 * 64;        // [B][16][64]
    float* c1f = h1f + (size_t)B_ * 16 * 64;
    float* h2f = c1f + (size_t)B_ * 16 * 64;             // [B][32][64]
    float* c2f = h2f + (size_t)B_ * 32 * 64;

    enc_kernel<<<B_, 256, 0, stream>>>(x, ew0, eb0, ew1, eb1, seq, h1f, c1f, h2f, c2f);
    dec0_kernel<<<B_, 256, 0, stream>>>(dw0, db0, seq, h2f, c2f);
    dec1_kernel<<<B_, 256, 0, stream>>>(dw1, db1, seq, h1f, c1f, fw, fb, out);
}

// Round 4
// 2940.916 us; speedup vs baseline: 1.0883x; 1.0883x over previous
//
#include <hip/hip_runtime.h>
#include <math.h>

#define B_ 128
#define T_ 100
#define RS 72      // padded row stride (words); data cols at [4..67]; [0..3],[68..71] zero

// ---------------------------------------------------------------------------
// Fast transcendentals (~1e-6 rel err; threshold 1.27e-4)
// ---------------------------------------------------------------------------
__device__ __forceinline__ float frcp_(float x){ return __builtin_amdgcn_rcpf(x); }
__device__ __forceinline__ float fsig_(float x){ return frcp_(1.f + __expf(-x)); }
__device__ __forceinline__ float ftanh_(float x){ float e = __expf(2.f*x); return 1.f - 2.f*frcp_(e+1.f); }
__device__ __forceinline__ float gate1(float zi, float zf, float zo, float zg, float& c){
    float cc = fsig_(zf)*c + fsig_(zi)*ftanh_(zg);
    c = cc;
    return fsig_(zo)*ftanh_(cc);
}
__device__ __forceinline__ void fma4v(float w, float u0,float u1,float u2,float u3, float4& a){
    a.x = fmaf(w,u0,a.x); a.y = fmaf(w,u1,a.y);
    a.z = fmaf(w,u2,a.z); a.w = fmaf(w,u3,a.w);
}
__device__ __forceinline__ void fma2v(float w, float u0,float u1, float2& a){
    a.x = fmaf(w,u0,a.x); a.y = fmaf(w,u1,a.y);
}

// ---------------------------------------------------------------------------
// Row accumulators. rowp = &buf[r*RS + 4 + f0] (16B-aligned for FT=4/8, 8B for FT=2).
// wk = wl + (krow*3)*ROWS + ch*4 ; tap d weight float4 at wk + d*ROWS.
// z[f] = w_tap0*v[f-1] + w_tap1*v[f] + w_tap2*v[f+1]
// ---------------------------------------------------------------------------
template<int ROWS>
__device__ __forceinline__ void rowacc4(const float* __restrict__ rowp,
                                        const float* __restrict__ wk,
                                        float4& ai, float4& af, float4& ao, float4& ag)
{
    float  m = rowp[-1];
    float4 a = *reinterpret_cast<const float4*>(rowp);
    float  p = rowp[4];
    float4 wa = *reinterpret_cast<const float4*>(wk);
    float4 wb = *reinterpret_cast<const float4*>(wk + ROWS);
    float4 wc = *reinterpret_cast<const float4*>(wk + 2*ROWS);
    fma4v(wa.x, m,a.x,a.y,a.z, ai);  fma4v(wa.y, m,a.x,a.y,a.z, af);
    fma4v(wa.z, m,a.x,a.y,a.z, ao);  fma4v(wa.w, m,a.x,a.y,a.z, ag);
    fma4v(wb.x, a.x,a.y,a.z,a.w, ai); fma4v(wb.y, a.x,a.y,a.z,a.w, af);
    fma4v(wb.z, a.x,a.y,a.z,a.w, ao); fma4v(wb.w, a.x,a.y,a.z,a.w, ag);
    fma4v(wc.x, a.y,a.z,a.w,p, ai);  fma4v(wc.y, a.y,a.z,a.w,p, af);
    fma4v(wc.z, a.y,a.z,a.w,p, ao);  fma4v(wc.w, a.y,a.z,a.w,p, ag);
}

template<int ROWS>
__device__ __forceinline__ void rowacc2(const float* __restrict__ rowp,
                                        const float* __restrict__ wk,
                                        float2& ai, float2& af, float2& ao, float2& ag)
{
    float  m = rowp[-1];
    float2 a = *reinterpret_cast<const float2*>(rowp);
    float  p = rowp[2];
    float4 wa = *reinterpret_cast<const float4*>(wk);
    float4 wb = *reinterpret_cast<const float4*>(wk + ROWS);
    float4 wc = *reinterpret_cast<const float4*>(wk + 2*ROWS);
    fma2v(wa.x, m,a.x, ai); fma2v(wa.y, m,a.x, af);
    fma2v(wa.z, m,a.x, ao); fma2v(wa.w, m,a.x, ag);
    fma2v(wb.x, a.x,a.y, ai); fma2v(wb.y, a.x,a.y, af);
    fma2v(wb.z, a.x,a.y, ao); fma2v(wb.w, a.x,a.y, ag);
    fma2v(wc.x, a.y,p, ai); fma2v(wc.y, a.y,p, af);
    fma2v(wc.z, a.y,p, ao); fma2v(wc.w, a.y,p, ag);
}

template<int ROWS>
__device__ __forceinline__ void rowacc8(const float* __restrict__ rowp,
                                        const float* __restrict__ wk,
                                        float4& i0, float4& i1, float4& f0v, float4& f1v,
                                        float4& o0, float4& o1, float4& g0, float4& g1)
{
    float  m = rowp[-1];
    float4 a = *reinterpret_cast<const float4*>(rowp);
    float4 b = *reinterpret_cast<const float4*>(rowp + 4);
    float  p = rowp[8];
    float4 wa = *reinterpret_cast<const float4*>(wk);
    float4 wb = *reinterpret_cast<const float4*>(wk + ROWS);
    float4 wc = *reinterpret_cast<const float4*>(wk + 2*ROWS);
    fma4v(wa.x, m,a.x,a.y,a.z, i0);   fma4v(wa.x, a.w,b.x,b.y,b.z, i1);
    fma4v(wa.y, m,a.x,a.y,a.z, f0v);  fma4v(wa.y, a.w,b.x,b.y,b.z, f1v);
    fma4v(wa.z, m,a.x,a.y,a.z, o0);   fma4v(wa.z, a.w,b.x,b.y,b.z, o1);
    fma4v(wa.w, m,a.x,a.y,a.z, g0);   fma4v(wa.w, a.w,b.x,b.y,b.z, g1);
    fma4v(wb.x, a.x,a.y,a.z,a.w, i0); fma4v(wb.x, b.x,b.y,b.z,b.w, i1);
    fma4v(wb.y, a.x,a.y,a.z,a.w, f0v);fma4v(wb.y, b.x,b.y,b.z,b.w, f1v);
    fma4v(wb.z, a.x,a.y,a.z,a.w, o0); fma4v(wb.z, b.x,b.y,b.z,b.w, o1);
    fma4v(wb.w, a.x,a.y,a.z,a.w, g0); fma4v(wb.w, b.x,b.y,b.z,b.w, g1);
    fma4v(wc.x, a.y,a.z,a.w,b.x, i0); fma4v(wc.x, b.y,b.z,b.w,p, i1);
    fma4v(wc.y, a.y,a.z,a.w,b.x, f0v);fma4v(wc.y, b.y,b.z,b.w,p, f1v);
    fma4v(wc.z, a.y,a.z,a.w,b.x, o0); fma4v(wc.z, b.y,b.z,b.w,p, o1);
    fma4v(wc.w, a.y,a.z,a.w,b.x, g0); fma4v(wc.w, b.y,b.z,b.w,p, g1);
}

// ---------------------------------------------------------------------------
// Kernel 1: fused encoder. L0: (1+16)->16 FT=2, L1: (16+32)->32 FT=4. 512 thr.
// ---------------------------------------------------------------------------
__global__ __launch_bounds__(512, 2) void enc_kernel(
    const float* __restrict__ x,
    const float* __restrict__ w0, const float* __restrict__ b0,
    const float* __restrict__ w1, const float* __restrict__ b1,
    float* __restrict__ seq,
    float* __restrict__ h1f, float* __restrict__ c1f,
    float* __restrict__ h2f, float* __restrict__ c2f)
{
    __shared__ float wl0[51 * 64];     // (ci*3+d)*64 + ch*4+g, ci<17
    __shared__ float wl1[144 * 128];   // ci<48
    __shared__ float bs0[64];
    __shared__ float bs1[128];
    __shared__ float xp[RS];
    __shared__ float h0p[16 * RS];
    __shared__ float h1p[32 * RS];

    const int tid = threadIdx.x;
    const int b = blockIdx.x;

    for (int idx = tid; idx < 51 * 64; idx += 512) {
        int k = idx >> 6, r = idx & 63;
        int ch = r >> 2, g = r & 3;
        int ci = k / 3, d = k - ci * 3;
        wl0[idx] = w0[((g * 16 + ch) * 17 + ci) * 9 + d * 3 + 1];
    }
    for (int idx = tid; idx < 144 * 128; idx += 512) {
        int k = idx >> 7, r = idx & 127;
        int ch = r >> 2, g = r & 3;
        int ci = k / 3, d = k - ci * 3;
        wl1[idx] = w1[((g * 32 + ch) * 48 + ci) * 9 + d * 3 + 1];
    }
    if (tid < 64) bs0[tid] = b0[tid];
    if (tid < 128) bs1[tid] = b1[tid];
    for (int i = tid; i < RS; i += 512) xp[i] = 0.f;
    for (int i = tid; i < 16 * RS; i += 512) h0p[i] = 0.f;
    for (int i = tid; i < 32 * RS; i += 512) h1p[i] = 0.f;
    __syncthreads();

    const int chA = tid >> 5, f0A = (tid & 31) * 2;   // L0
    const int chB = tid >> 4, f0B = (tid & 15) * 4;   // L1

    const float biA = bs0[chA], bfA = bs0[16 + chA], boA = bs0[32 + chA], bgA = bs0[48 + chA];
    const float biB = bs1[chB], bfB = bs1[32 + chB], boB = bs1[64 + chB], bgB = bs1[96 + chB];

    const float4 z4 = make_float4(0.f,0.f,0.f,0.f);
    const float2 z2 = make_float2(0.f,0.f);
    float2 cA = z2, hh = z2;
    float4 cB = z4, cB1 = z4, hn0 = z4, hn1 = z4;
    // FT=4 on L1 gives 4 cols; cB is c for those 4 cols. (cB1/hn1 unused placeholders removed)
    (void)cB1; (void)hn1;

    float xv = (tid < 64) ? x[(b * T_ + 0) * 64 + tid] : 0.f;

#pragma unroll 1
    for (int t = 0; t < T_; ++t) {
        if (tid < 64) xp[4 + tid] = xv;
        __syncthreads();                                   // A
        if (tid < 64 && t + 1 < T_) xv = x[(b * T_ + t + 1) * 64 + tid];

        // ---- layer 0 (FT=2) ----
        float2 ai = z2, af = z2, ao = z2, ag = z2;
        rowacc2<64>(&xp[4 + f0A], wl0 + chA * 4, ai, af, ao, ag);
#pragma unroll 1
        for (int r = 0; r < 16; ++r)
            rowacc2<64>(&h0p[r * RS + 4 + f0A], wl0 + ((1 + r) * 3) * 64 + chA * 4,
                        ai, af, ao, ag);

        hh.x = gate1(ai.x + biA, af.x + bfA, ao.x + boA, ag.x + bgA, cA.x);
        hh.y = gate1(ai.y + biA, af.y + bfA, ao.y + boA, ag.y + bgA, cA.y);
        __syncthreads();                                   // B
        *reinterpret_cast<float2*>(&h0p[chA * RS + 4 + f0A]) = hh;
        __syncthreads();                                   // C

        // ---- layer 1 (FT=4) ----
        float4 bi4 = z4, bf4 = z4, bo4 = z4, bg4 = z4;
#pragma unroll 1
        for (int r = 0; r < 16; ++r)
            rowacc4<128>(&h0p[r * RS + 4 + f0B], wl1 + (r * 3) * 128 + chB * 4,
                         bi4, bf4, bo4, bg4);
#pragma unroll 1
        for (int r = 0; r < 32; ++r)
            rowacc4<128>(&h1p[r * RS + 4 + f0B], wl1 + ((16 + r) * 3) * 128 + chB * 4,
                         bi4, bf4, bo4, bg4);

        hn0.x = gate1(bi4.x + biB, bf4.x + bfB, bo4.x + boB, bg4.x + bgB, cB.x);
        hn0.y = gate1(bi4.y + biB, bf4.y + bfB, bo4.y + boB, bg4.y + bgB, cB.y);
        hn0.z = gate1(bi4.z + biB, bf4.z + bfB, bo4.z + boB, bg4.z + bgB, cB.z);
        hn0.w = gate1(bi4.w + biB, bf4.w + bfB, bo4.w + boB, bg4.w + bgB, cB.w);
        __syncthreads();                                   // D
        *reinterpret_cast<float4*>(&h1p[chB * RS + 4 + f0B]) = hn0;
        *reinterpret_cast<float4*>(&seq[(((size_t)t * B_ + b) * 32 + chB) * 64 + f0B]) = hn0;
    }

    *reinterpret_cast<float2*>(&h1f[(b * 16 + chA) * 64 + f0A]) = hh;
    *reinterpret_cast<float2*>(&c1f[(b * 16 + chA) * 64 + f0A]) = cA;
    *reinterpret_cast<float4*>(&h2f[(b * 32 + chB) * 64 + f0B]) = hn0;
    *reinterpret_cast<float4*>(&c2f[(b * 32 + chB) * 64 + f0B]) = cB;
}

// ---------------------------------------------------------------------------
// P0: parallel x-part pre-activations for dec0. One block per (t,b).
// zx[tl][b][g][32][64] += conv_x(seq_enc). No bias.
// ---------------------------------------------------------------------------
__global__ __launch_bounds__(256, 2) void xconv0_kernel(
    const float* __restrict__ seqIn, const float* __restrict__ w,
    float* __restrict__ zx, int t0)
{
    __shared__ float wl[96 * 128];     // ci<32 (x rows only)
    __shared__ float xt[32 * RS];

    const int tid = threadIdx.x;
    const int tl = blockIdx.x / B_;
    const int b  = blockIdx.x - tl * B_;
    const int t  = t0 + tl;

    for (int idx = tid; idx < 96 * 128; idx += 256) {
        int k = idx >> 7, r = idx & 127;
        int ch = r >> 2, g = r & 3;
        int ci = k / 3, d = k - ci * 3;
        wl[idx] = w[((g * 32 + ch) * 64 + ci) * 9 + d * 3 + 1];
    }
    {   // zero pads (disjoint from data, no barrier needed before staging)
        int r = tid >> 3, j = tid & 7;
        xt[r * RS + (j < 4 ? j : 64 + j)] = 0.f;
    }
    {   // stage x tile: 8 floats per thread
        const float* s = &seqIn[((size_t)t * B_ + b) * 2048 + tid * 8];
        float4 v0 = *reinterpret_cast<const float4*>(s);
        float4 v1 = *reinterpret_cast<const float4*>(s + 4);
        int ci = tid >> 3, col = (tid & 7) * 8;
        *reinterpret_cast<float4*>(&xt[ci * RS + 4 + col])     = v0;
        *reinterpret_cast<float4*>(&xt[ci * RS + 4 + col + 4]) = v1;
    }
    __syncthreads();

    const int ch = tid >> 3, f0 = (tid & 7) * 8;
    const float4 z4 = make_float4(0.f,0.f,0.f,0.f);
    float4 i0=z4,i1=z4,f0v=z4,f1v=z4,o0=z4,o1=z4,g0=z4,g1=z4;
#pragma unroll 1
    for (int r = 0; r < 32; ++r)
        rowacc8<128>(&xt[r * RS + 4 + f0], wl + (r * 3) * 128 + ch * 4,
                     i0, i1, f0v, f1v, o0, o1, g0, g1);

    float* zp = &zx[(((size_t)tl * B_ + b) * 4) * 2048 + ch * 64 + f0];
    *reinterpret_cast<float4*>(zp)              = i0;
    *reinterpret_cast<float4*>(zp + 4)          = i1;
    *reinterpret_cast<float4*>(zp + 2048)       = f0v;
    *reinterpret_cast<float4*>(zp + 2048 + 4)   = f1v;
    *reinterpret_cast<float4*>(zp + 4096)       = o0;
    *reinterpret_cast<float4*>(zp + 4096 + 4)   = o1;
    *reinterpret_cast<float4*>(zp + 6144)       = g0;
    *reinterpret_cast<float4*>(zp + 6144 + 4)   = g1;
}

// ---------------------------------------------------------------------------
// P1: parallel x-part for dec1 (32 -> 16ch). One block per (t,b).
// ---------------------------------------------------------------------------
__global__ __launch_bounds__(256, 2) void xconv1_kernel(
    const float* __restrict__ seqIn, const float* __restrict__ w,
    float* __restrict__ zx, int t0)
{
    __shared__ float wl[96 * 64];      // ci<32
    __shared__ float xt[32 * RS];

    const int tid = threadIdx.x;
    const int tl = blockIdx.x / B_;
    const int b  = blockIdx.x - tl * B_;
    const int t  = t0 + tl;

    for (int idx = tid; idx < 96 * 64; idx += 256) {
        int k = idx >> 6, r = idx & 63;
        int ch = r >> 2, g = r & 3;
        int ci = k / 3, d = k - ci * 3;
        wl[idx] = w[((g * 16 + ch) * 48 + ci) * 9 + d * 3 + 1];
    }
    {
        int r = tid >> 3, j = tid & 7;
        xt[r * RS + (j < 4 ? j : 64 + j)] = 0.f;
    }
    {
        const float* s = &seqIn[((size_t)t * B_ + b) * 2048 + tid * 8];
        float4 v0 = *reinterpret_cast<const float4*>(s);
        float4 v1 = *reinterpret_cast<const float4*>(s + 4);
        int ci = tid >> 3, col = (tid & 7) * 8;
        *reinterpret_cast<float4*>(&xt[ci * RS + 4 + col])     = v0;
        *reinterpret_cast<float4*>(&xt[ci * RS + 4 + col + 4]) = v1;
    }
    __syncthreads();

    const int ch = tid >> 4, f0 = (tid & 15) * 4;
    const float4 z4 = make_float4(0.f,0.f,0.f,0.f);
    float4 ai=z4, af=z4, ao=z4, ag=z4;
#pragma unroll 1
    for (int r = 0; r < 32; ++r)
        rowacc4<64>(&xt[r * RS + 4 + f0], wl + (r * 3) * 64 + ch * 4, ai, af, ao, ag);

    float* zp = &zx[(((size_t)tl * B_ + b) * 4) * 1024 + ch * 64 + f0];
    *reinterpret_cast<float4*>(zp)        = ai;
    *reinterpret_cast<float4*>(zp + 1024) = af;
    *reinterpret_cast<float4*>(zp + 2048) = ao;
    *reinterpret_cast<float4*>(zp + 3072) = ag;
}

// ---------------------------------------------------------------------------
// Kernel: decoder L0 (32+32)->32, FT=4, 512 thr. PRE: h-part only, x from zx.
// ---------------------------------------------------------------------------
template<bool PRE>
__global__ __launch_bounds__(512, 2) void dec0_kernel(
    const float* __restrict__ w, const float* __restrict__ bias,
    float* __restrict__ seq, const float* __restrict__ zx,
    const float* __restrict__ hin, const float* __restrict__ cin,
    float* __restrict__ hout, float* __restrict__ cout,
    int t0, int tn)
{
    __shared__ float wl[192 * 128];    // ci<64 (x 0..31, h 32..63)
    __shared__ float bs[128];
    __shared__ float xin[32 * RS];
    __shared__ float hp[32 * RS];

    const int tid = threadIdx.x;
    const int b = blockIdx.x;

    const int wstart = PRE ? 96 * 128 : 0;
    for (int idx = wstart + tid; idx < 192 * 128; idx += 512) {
        int k = idx >> 7, r = idx & 127;
        int ch = r >> 2, g = r & 3;
        int ci = k / 3, d = k - ci * 3;
        wl[idx] = w[((g * 32 + ch) * 64 + ci) * 9 + d * 3 + 1];
    }
    if (tid < 128) bs[tid] = bias[tid];
    for (int i = tid; i < 32 * RS; i += 512) { xin[i] = 0.f; hp[i] = 0.f; }
    __syncthreads();
    {   // h init
        const float* hs = &hin[b * 2048 + tid * 4];
        float4 hv = *reinterpret_cast<const float4*>(hs);
        int ci = tid >> 4, col = (tid & 15) * 4;
        *reinterpret_cast<float4*>(&hp[ci * RS + 4 + col]) = hv;
    }
    const int ch = tid >> 4, f0 = (tid & 15) * 4;
    float4 cc = *reinterpret_cast<const float4*>(&cin[b * 2048 + ch * 64 + f0]);
    const float bi = bs[ch], bf = bs[32 + ch], bo = bs[64 + ch], bg = bs[96 + ch];
    const float4 z4 = make_float4(0.f,0.f,0.f,0.f);
    float4 hn = z4;

    float4 zi = z4, zf = z4, zo = z4, zg = z4;
    float4 nx = z4;
    if (PRE) {
        const float* zp = &zx[((size_t)0 * B_ + b) * 8192 + ch * 64 + f0];
        zi = *reinterpret_cast<const float4*>(zp);
        zf = *reinterpret_cast<const float4*>(zp + 2048);
        zo = *reinterpret_cast<const float4*>(zp + 4096);
        zg = *reinterpret_cast<const float4*>(zp + 6144);
    } else {
        nx = *reinterpret_cast<const float4*>(&seq[((size_t)t0 * B_ + b) * 2048 + tid * 4]);
    }

#pragma unroll 1
    for (int tl = 0; tl < tn; ++tl) {
        const int t = t0 + tl;
        if (!PRE) {
            int ci = tid >> 4, col = (tid & 15) * 4;
            *reinterpret_cast<float4*>(&xin[ci * RS + 4 + col]) = nx;
        }
        __syncthreads();                                   // A
        // prefetch next chunk of inputs
        if (PRE) {
            if (tl + 1 < tn) {
                const float* zp = &zx[((size_t)(tl + 1) * B_ + b) * 8192 + ch * 64 + f0];
                float4 a0 = zi, a1 = zf, a2 = zo, a3 = zg;
                zi = *reinterpret_cast<const float4*>(zp);
                zf = *reinterpret_cast<const float4*>(zp + 2048);
                zo = *reinterpret_cast<const float4*>(zp + 4096);
                zg = *reinterpret_cast<const float4*>(zp + 6144);
                // use previous values below via a0..a3
                float4 ai = a0, af = a1, ao = a2, ag = a3;
#pragma unroll 1
                for (int r = 0; r < 32; ++r)
                    rowacc4<128>(&hp[r * RS + 4 + f0], wl + ((32 + r) * 3) * 128 + ch * 4,
                                 ai, af, ao, ag);
                hn.x = gate1(ai.x + bi, af.x + bf, ao.x + bo, ag.x + bg, cc.x);
                hn.y = gate1(ai.y + bi, af.y + bf, ao.y + bo, ag.y + bg, cc.y);
                hn.z = gate1(ai.z + bi, af.z + bf, ao.z + bo, ag.z + bg, cc.z);
                hn.w = gate1(ai.w + bi, af.w + bf, ao.w + bo, ag.w + bg, cc.w);
            } else {
                float4 ai = zi, af = zf, ao = zo, ag = zg;
#pragma unroll 1
                for (int r = 0; r < 32; ++r)
                    rowacc4<128>(&hp[r * RS + 4 + f0], wl + ((32 + r) * 3) * 128 + ch * 4,
                                 ai, af, ao, ag);
                hn.x = gate1(ai.x + bi, af.x + bf, ao.x + bo, ag.x + bg, cc.x);
                hn.y = gate1(ai.y + bi, af.y + bf, ao.y + bo, ag.y + bg, cc.y);
                hn.z = gate1(ai.z + bi, af.z + bf, ao.z + bo, ag.z + bg, cc.z);
                hn.w = gate1(ai.w + bi, af.w + bf, ao.w + bo, ag.w + bg, cc.w);
            }
        } else {
            if (tl + 1 < tn)
                nx = *reinterpret_cast<const float4*>(
                    &seq[((size_t)(t + 1) * B_ + b) * 2048 + tid * 4]);
            float4 ai = z4, af = z4, ao = z4, ag = z4;
#pragma unroll 1
            for (int r = 0; r < 32; ++r)
                rowacc4<128>(&xin[r * RS + 4 + f0], wl + (r * 3) * 128 + ch * 4,
                             ai, af, ao, ag);
#pragma unroll 1
            for (int r = 0; r < 32; ++r)
                rowacc4<128>(&hp[r * RS + 4 + f0], wl + ((32 + r) * 3) * 128 + ch * 4,
                             ai, af, ao, ag);
            hn.x = gate1(ai.x + bi, af.x + bf, ao.x + bo, ag.x + bg, cc.x);
            hn.y = gate1(ai.y + bi, af.y + bf, ao.y + bo, ag.y + bg, cc.y);
            hn.z = gate1(ai.z + bi, af.z + bf, ao.z + bo, ag.z + bg, cc.z);
            hn.w = gate1(ai.w + bi, af.w + bf, ao.w + bo, ag.w + bg, cc.w);
        }
        __syncthreads();                                   // B
        *reinterpret_cast<float4*>(&hp[ch * RS + 4 + f0]) = hn;
        *reinterpret_cast<float4*>(&seq[((size_t)t * B_ + b) * 2048 + ch * 64 + f0]) = hn;
    }

    *reinterpret_cast<float4*>(&hout[b * 2048 + ch * 64 + f0]) = hn;
    *reinterpret_cast<float4*>(&cout[b * 2048 + ch * 64 + f0]) = cc;
}

// ---------------------------------------------------------------------------
// Kernel: decoder L1 (32+16)->16, FT=2, 512 thr + final 1x1 conv.
// ---------------------------------------------------------------------------
template<bool PRE>
__global__ __launch_bounds__(512, 2) void dec1_kernel(
    const float* __restrict__ w, const float* __restrict__ bias,
    const float* __restrict__ seq, const float* __restrict__ zx,
    const float* __restrict__ hin, const float* __restrict__ cin,
    float* __restrict__ hout, float* __restrict__ cout,
    const float* __restrict__ fw, const float* __restrict__ fb,
    float* __restrict__ out, int t0, int tn)
{
    __shared__ float wl[144 * 64];     // ci<48 (x 0..31, h 32..47)
    __shared__ float bs[64];
    __shared__ float xin[32 * RS];
    __shared__ float hp[16 * RS];
    __shared__ float fcw[16];
    __shared__ float fcb;

    const int tid = threadIdx.x;
    const int b = blockIdx.x;

    const int wstart = PRE ? 96 * 64 : 0;
    for (int idx = wstart + tid; idx < 144 * 64; idx += 512) {
        int k = idx >> 6, r = idx & 63;
        int ch = r >> 2, g = r & 3;
        int ci = k / 3, d = k - ci * 3;
        wl[idx] = w[((g * 16 + ch) * 48 + ci) * 9 + d * 3 + 1];
    }
    if (tid < 64) bs[tid] = bias[tid];
    if (tid < 16) fcw[tid] = fw[tid];
    if (tid == 16) fcb = fb[0];
    for (int i = tid; i < 32 * RS; i += 512) xin[i] = 0.f;
    for (int i = tid; i < 16 * RS; i += 512) hp[i] = 0.f;
    __syncthreads();
    {   // h init (1024 floats, 2 per thread)
        const float* hs = &hin[b * 1024 + tid * 2];
        float2 hv = *reinterpret_cast<const float2*>(hs);
        int ci = tid >> 5, col = (tid & 31) * 2;
        *reinterpret_cast<float2*>(&hp[ci * RS + 4 + col]) = hv;
    }
    const int ch = tid >> 5, f0 = (tid & 31) * 2;
    float2 cc = *reinterpret_cast<const float2*>(&cin[b * 1024 + ch * 64 + f0]);
    const float bi = bs[ch], bf = bs[16 + ch], bo = bs[32 + ch], bg = bs[48 + ch];
    const float2 z2 = make_float2(0.f,0.f);
    const float4 z4 = make_float4(0.f,0.f,0.f,0.f);
    float2 hh = z2;

    float2 zi = z2, zf = z2, zo = z2, zg = z2;
    float4 nx = z4;
    if (PRE) {
        const float* zp = &zx[((size_t)0 * B_ + b) * 4096 + ch * 64 + f0];
        zi = *reinterpret_cast<const float2*>(zp);
        zf = *reinterpret_cast<const float2*>(zp + 1024);
        zo = *reinterpret_cast<const float2*>(zp + 2048);
        zg = *reinterpret_cast<const float2*>(zp + 3072);
    } else {
        nx = *reinterpret_cast<const float4*>(&seq[((size_t)t0 * B_ + b) * 2048 + tid * 4]);
    }
    __syncthreads();

#pragma unroll 1
    for (int tl = 0; tl < tn; ++tl) {
        const int t = t0 + tl;
        if (!PRE) {
            int ci = tid >> 4, col = (tid & 15) * 4;
            *reinterpret_cast<float4*>(&xin[ci * RS + 4 + col]) = nx;
            __syncthreads();                               // A (xin staged)
            if (tl + 1 < tn)
                nx = *reinterpret_cast<const float4*>(
                    &seq[((size_t)(t + 1) * B_ + b) * 2048 + tid * 4]);
        }

        float2 ai, af, ao, ag;
        if (PRE) {
            ai = zi; af = zf; ao = zo; ag = zg;
            if (tl + 1 < tn) {
                const float* zp = &zx[((size_t)(tl + 1) * B_ + b) * 4096 + ch * 64 + f0];
                zi = *reinterpret_cast<const float2*>(zp);
                zf = *reinterpret_cast<const float2*>(zp + 1024);
                zo = *reinterpret_cast<const float2*>(zp + 2048);
                zg = *reinterpret_cast<const float2*>(zp + 3072);
            }
        } else {
            ai = z2; af = z2; ao = z2; ag = z2;
#pragma unroll 1
            for (int r = 0; r < 32; ++r)
                rowacc2<64>(&xin[r * RS + 4 + f0], wl + (r * 3) * 64 + ch * 4,
                            ai, af, ao, ag);
        }
#pragma unroll 1
        for (int r = 0; r < 16; ++r)
            rowacc2<64>(&hp[r * RS + 4 + f0], wl + ((32 + r) * 3) * 64 + ch * 4,
                        ai, af, ao, ag);

        hh.x = gate1(ai.x + bi, af.x + bf, ao.x + bo, ag.x + bg, cc.x);
        hh.y = gate1(ai.y + bi, af.y + bf, ao.y + bo, ag.y + bg, cc.y);
        __syncthreads();                                   // B
        *reinterpret_cast<float2*>(&hp[ch * RS + 4 + f0]) = hh;
        __syncthreads();                                   // C

        if (tid < 64) {
            float a = fcb;
#pragma unroll
            for (int k2 = 0; k2 < 16; ++k2)
                a = fmaf(fcw[k2], hp[k2 * RS + 4 + tid], a);
            out[(b * T_ + t) * 64 + tid] = a;
        }
    }

    *reinterpret_cast<float2*>(&hout[b * 1024 + ch * 64 + f0]) = hh;
    *reinterpret_cast<float2*>(&cout[b * 1024 + ch * 64 + f0]) = cc;
}

// ---------------------------------------------------------------------------
extern "C" void kernel_launch(void* const* d_in, const int* in_sizes, int n_in,
                              void* d_out, int out_size, void* d_ws, size_t ws_size,
                              hipStream_t stream)
{
    (void)in_sizes; (void)n_in; (void)out_size;
    const float* x   = (const float*)d_in[0];
    const float* ew0 = (const float*)d_in[1];
    const float* eb0 = (const float*)d_in[2];
    const float* ew1 = (const float*)d_in[3];
    const float* eb1 = (const float*)d_in[4];
    const float* dw0 = (const float*)d_in[5];
    const float* db0 = (const float*)d_in[6];
    const float* dw1 = (const float*)d_in[7];
    const float* db1 = (const float*)d_in[8];
    const float* fw  = (const float*)d_in[9];
    const float* fb  = (const float*)d_in[10];
    float* out = (float*)d_out;

    float* ws  = (float*)d_ws;
    size_t off = 0;
    float* seq = ws + off; off += (size_t)T_ * B_ * 2048;   // enc2 / dec0 hidden seq
    float* h1f = ws + off; off += (size_t)B_ * 1024;
    float* c1f = ws + off; off += (size_t)B_ * 1024;
    float* h2f = ws + off; off += (size_t)B_ * 2048;
    float* c2f = ws + off; off += (size_t)B_ * 2048;
    float* hd0 = ws + off; off += (size_t)B_ * 2048;
    float* cd0 = ws + off; off += (size_t)B_ * 2048;
    float* hd1 = ws + off; off += (size_t)B_ * 1024;
    float* cd1 = ws + off; off += (size_t)B_ * 1024;
    float* zx  = ws + off;

    size_t availf = (ws_size / 4 > off) ? (ws_size / 4 - off) : 0;
    int TC = 0;
    if      (availf >= (size_t)100 * B_ * 8192) TC = 100;
    else if (availf >= (size_t)50  * B_ * 8192) TC = 50;
    else if (availf >= (size_t)25  * B_ * 8192) TC = 25;
    else if (availf >= (size_t)10  * B_ * 8192) TC = 10;

    enc_kernel<<<B_, 512, 0, stream>>>(x, ew0, eb0, ew1, eb1, seq, h1f, c1f, h2f, c2f);

    if (TC > 0) {
        for (int t0 = 0; t0 < T_; t0 += TC) {
            xconv0_kernel<<<TC * B_, 256, 0, stream>>>(seq, dw0, zx, t0);
            dec0_kernel<true><<<B_, 512, 0, stream>>>(
                dw0, db0, seq, zx,
                t0 == 0 ? h2f : hd0, t0 == 0 ? c2f : cd0, hd0, cd0, t0, TC);
        }
        for (int t0 = 0; t0 < T_; t0 += TC) {
            xconv1_kernel<<<TC * B_, 256, 0, stream>>>(seq, dw1, zx, t0);
            dec1_kernel<true><<<B_, 512, 0, stream>>>(
                dw1, db1, seq, zx,
                t0 == 0 ? h1f : hd1, t0 == 0 ? c1f : cd1, hd1, cd1,
                fw, fb, out, t0, TC);
        }
    } else {
        dec0_kernel<false><<<B_, 512, 0, stream>>>(
            dw0, db0, seq, nullptr, h2f, c2f, hd0, cd0, 0, T_);
        dec1_kernel<false><<<B_, 512, 0, stream>>>(
            dw1, db1, seq, nullptr, h1f, c1f, hd1, cd1, fw, fb, out, 0, T_);
    }
}